// Round 15
// baseline (176.207 us; speedup 1.0000x reference)
//
#include <hip/hip_runtime.h>
#include <hip/hip_bf16.h>

typedef float f32x4 __attribute__((ext_vector_type(4)));
typedef float f32x16 __attribute__((ext_vector_type(16)));
typedef unsigned int u32;
typedef u32 u32x2 __attribute__((ext_vector_type(2)));
typedef u32 u32x4 __attribute__((ext_vector_type(4)));
typedef short bf16x8 __attribute__((ext_vector_type(8)));

#define SD 8192      // S*D
#define NROWS 8192   // B*N
#define NN 4096      // N
#define DD 2048      // D
#define DTP 4104     // padded u32 row stride for dT

__device__ __forceinline__ u32 bfr(float f) {   // f32 -> bf16 bits, RNE (K0 only)
    u32 u = __float_as_uint(f);
    return (u + 0x7fffu + ((u >> 16) & 1u)) >> 16;
}
__device__ __forceinline__ float blo(u32 u) { return __uint_as_float(u << 16); }
__device__ __forceinline__ float bhi(u32 u) { return __uint_as_float(u & 0xffff0000u); }

// K0: weights in MFMA B-fragment order (R14-verified):
//   Wfrag[((wv*64+st)*64+lane)*8+e] = W[k=lane&31][j=wv*1024+st*16+((lane>>5)&1)*8+e]
__global__ void k0_prep(const float* __restrict__ gamma,
                        const float* __restrict__ daf,
                        const float* __restrict__ dbf,
                        unsigned short* __restrict__ Wfrag) {
    int idx = blockIdx.x * 256 + threadIdx.x;
    if (idx >= 32 * SD) return;
    const int e    = idx & 7;
    const int lane = (idx >> 3) & 63;
    const int st   = (idx >> 9) & 63;
    const int wv   = idx >> 15;
    const int outk = lane & 31;
    const int j    = wv * 1024 + st * 16 + ((lane >> 5) & 1) * 8 + e;
    unsigned short v = 0;
    if (outk < 24) {
        float g = gamma[j] + 1.0f;
        float w = (outk < 20) ? daf[j * 20 + outk] : dbf[j * 4 + (outk - 20)];
        v = (unsigned short)bfr(w * g);
    }
    Wfrag[idx] = v;
}

// KF: fused; WAVE-PRIVATE stage->MFMA pipeline (no P1/P2 barrier).
// Wave wv owns j-slice [wv*1024,(wv+1)*1024) of all 4 rows: stages it
// (f32->bf16->LDS) in 4 segments of 256, MFMA-ing segment i-1 while segment
// i's global loads are in flight (T14 split). B = fragment-order Wfrag
// (coalesced, L2-resident). Barriers only before/after pc-reduce + P3.
// Loads cacheable (L3 retention across replays); stores nontemporal.
__global__ __launch_bounds__(512) void kf(const float* __restrict__ res,
                                          const unsigned short* __restrict__ Wfrag,
                                          const float* __restrict__ sa,
                                          const float* __restrict__ sb,
                                          const float* __restrict__ pbs,
                                          const float* __restrict__ rsc,
                                          const float* __restrict__ hps,
                                          float* __restrict__ out) {
    __shared__ u32 dTp[4][DTP];        // packed bf16x2; 65.7 KiB
    __shared__ float pc[8][4][32];     // per-wave partial C
    __shared__ float red[4][32];
    __shared__ float ssqp[8][4];       // per-wave partial ssq per row
    __shared__ float coefS[4][16];

    const int tid  = threadIdx.x;
    const int wv   = tid >> 6;
    const int lane = tid & 63;
    const int row0 = blockIdx.x * 4;
    const int b    = row0 >> 12;
    const int n0   = row0 & (NN - 1);
    const int r    = tid >> 7;          // P4 row 0..3
    const int rem  = tid & 127;

    // ---------- P1+P2: wave-private pipelined stage + MFMA ----------
    {
        const int sp = wv >> 1;                     // this wave's s-plane
        const int d0 = (wv & 1) * 1024;             // d-offset of slice
        const float* rp0 = res + ((size_t)(b * 4 + sp) * NN + n0) * DD + d0 + lane * 4;
        const float* rp1 = rp0 + DD;
        const float* rp2 = rp0 + 2 * DD;
        const float* rp3 = rp0 + 3 * DD;

        f32x16 acc;
#pragma unroll
        for (int i = 0; i < 16; ++i) acc[i] = 0.f;
        float sq0 = 0.f, sq1 = 0.f, sq2 = 0.f, sq3 = 0.f;
        const u32* abase = &dTp[lane & 3][wv * 512 + (lane >> 5) * 4];
        const unsigned short* wbase = Wfrag + ((size_t)wv * 4096 + lane) * 8;

        f32x4 v0, v1, v2, v3;
#define SG_LOAD(i)                                                            \
        do {                                                                  \
            v0 = *(const f32x4*)(rp0 + (i) * 256);                            \
            v1 = *(const f32x4*)(rp1 + (i) * 256);                            \
            v2 = *(const f32x4*)(rp2 + (i) * 256);                            \
            v3 = *(const f32x4*)(rp3 + (i) * 256);                            \
        } while (0)
#define SG_FIN(i)                                                             \
        do {                                                                  \
            sq0 += v0.x * v0.x + v0.y * v0.y + v0.z * v0.z + v0.w * v0.w;     \
            sq1 += v1.x * v1.x + v1.y * v1.y + v1.z * v1.z + v1.w * v1.w;     \
            sq2 += v2.x * v2.x + v2.y * v2.y + v2.z * v2.z + v2.w * v2.w;     \
            sq3 += v3.x * v3.x + v3.y * v3.y + v3.z * v3.z + v3.w * v3.w;     \
            const int o = wv * 512 + (i) * 128 + lane * 2;                    \
            u32 lo, hi;                                                       \
            asm("v_cvt_pk_bf16_f32 %0, %1, %2" : "=v"(lo) : "v"(v0.x), "v"(v0.y)); \
            asm("v_cvt_pk_bf16_f32 %0, %1, %2" : "=v"(hi) : "v"(v0.z), "v"(v0.w)); \
            *(u32x2*)&dTp[0][o] = (u32x2){lo, hi};                            \
            asm("v_cvt_pk_bf16_f32 %0, %1, %2" : "=v"(lo) : "v"(v1.x), "v"(v1.y)); \
            asm("v_cvt_pk_bf16_f32 %0, %1, %2" : "=v"(hi) : "v"(v1.z), "v"(v1.w)); \
            *(u32x2*)&dTp[1][o] = (u32x2){lo, hi};                            \
            asm("v_cvt_pk_bf16_f32 %0, %1, %2" : "=v"(lo) : "v"(v2.x), "v"(v2.y)); \
            asm("v_cvt_pk_bf16_f32 %0, %1, %2" : "=v"(hi) : "v"(v2.z), "v"(v2.w)); \
            *(u32x2*)&dTp[2][o] = (u32x2){lo, hi};                            \
            asm("v_cvt_pk_bf16_f32 %0, %1, %2" : "=v"(lo) : "v"(v3.x), "v"(v3.y)); \
            asm("v_cvt_pk_bf16_f32 %0, %1, %2" : "=v"(hi) : "v"(v3.z), "v"(v3.w)); \
            *(u32x2*)&dTp[3][o] = (u32x2){lo, hi};                            \
        } while (0)
#define MM(seg)                                                               \
        do {                                                                  \
            _Pragma("unroll")                                                 \
            for (int g = 0; g < 2; ++g) {                                     \
                u32x4 bu[8];                                                  \
                _Pragma("unroll")                                             \
                for (int s8 = 0; s8 < 8; ++s8)                                \
                    bu[s8] = *(const u32x4*)(wbase + (size_t)((seg) * 16 + g * 8 + s8) * 512); \
                _Pragma("unroll")                                             \
                for (int s8 = 0; s8 < 8; ++s8) {                              \
                    const u32x4 au = *(const u32x4*)(abase + ((seg) * 16 + g * 8 + s8) * 8); \
                    acc = __builtin_amdgcn_mfma_f32_32x32x16_bf16(            \
                        __builtin_bit_cast(bf16x8, au),                       \
                        __builtin_bit_cast(bf16x8, bu[s8]), acc, 0, 0, 0);    \
                }                                                             \
            }                                                                 \
        } while (0)

        SG_LOAD(0); SG_FIN(0);
        SG_LOAD(1); MM(0); SG_FIN(1);
        SG_LOAD(2); MM(1); SG_FIN(2);
        SG_LOAD(3); MM(2); SG_FIN(3);
        MM(3);
#undef SG_LOAD
#undef SG_FIN
#undef MM

        // reduce ssq partials across the wave's 64 lanes
#define RED64(x) x += __shfl_xor(x, 1); x += __shfl_xor(x, 2); x += __shfl_xor(x, 4); \
                 x += __shfl_xor(x, 8); x += __shfl_xor(x, 16); x += __shfl_xor(x, 32);
        RED64(sq0) RED64(sq1) RED64(sq2) RED64(sq3)
#undef RED64
        if (lane == 0) {
            ssqp[wv][0] = sq0; ssqp[wv][1] = sq1;
            ssqp[wv][2] = sq2; ssqp[wv][3] = sq3;
        }
        if (lane < 32) {
#pragma unroll
            for (int gg = 0; gg < 4; ++gg) pc[wv][gg][lane] = acc[gg];
        }
    }
    __syncthreads();
    if (tid < 128) {
        const int rr = tid >> 5, c = tid & 31;
        float s = 0.f;
#pragma unroll
        for (int w = 0; w < 8; ++w) s += pc[w][rr][c];
        red[rr][c] = s;
    }
    __syncthreads();

    // ---------- P3: sinkhorn + coeff (wave 0; 4 rows x 16 lanes) ----------
    if (wv == 0) {
        const int rr = lane >> 4, l = lane & 15, s = l >> 2, t = l & 3;
        float ssqr = 0.f;
#pragma unroll
        for (int w = 0; w < 8; ++w) ssqr += ssqp[w][rr];
        const float scale = 90.50966799187809f / fmaxf(sqrtf(ssqr), 1e-12f);
        const float P  = red[rr][s * 5 + t + 1];
        const float P0 = red[rr][s * 5];
        const float Pb = red[rr][20 + t];
        float la = scale * P * rsc[0] + sa[s * 5 + t + 1];
        const float a0 = scale * P0 * pbs[0] + sa[s * 5];
        const float ap = 1.f / (1.f + __expf(-a0));
        const float bt = 2.f / (1.f + __expf(-(scale * Pb * hps[0] + sb[t])));
#pragma unroll
        for (int it = 0; it < 20; ++it) {
            float m = fmaxf(la, __shfl_xor(la, 4));
            m = fmaxf(m, __shfl_xor(m, 8));
            float e = __expf(la - m);
            e += __shfl_xor(e, 4);
            e += __shfl_xor(e, 8);
            la -= m + __logf(e);
            m = fmaxf(la, __shfl_xor(la, 1));
            m = fmaxf(m, __shfl_xor(m, 2));
            e = __expf(la - m);
            e += __shfl_xor(e, 1);
            e += __shfl_xor(e, 2);
            la -= m + __logf(e);
        }
        coefS[rr][t * 4 + s] = ap * bt + __expf(la);
    }
    __syncthreads();

    // ---------- P4: mix + store (rolled, packed FMA) ----------
    float cf[16];
#pragma unroll
    for (int i = 0; i < 16; ++i) cf[i] = coefS[r][i];
    float* ob = out + ((size_t)(b * 4) * NN + (n0 + r)) * DD;
#pragma unroll 1
    for (int qq = 0; qq < 4; ++qq) {
        const int dp = (rem + 128 * qq) * 2;    // u32 index within s-plane
        f32x4 dv4[4];
#pragma unroll
        for (int s = 0; s < 4; ++s) {
            u32x2 u = *(const u32x2*)&dTp[r][s * 1024 + dp];
            dv4[s] = (f32x4){blo(u[0]), bhi(u[0]), blo(u[1]), bhi(u[1])};
        }
#pragma unroll
        for (int t = 0; t < 4; ++t) {
            f32x4 o = cf[t * 4 + 0] * dv4[0];
            o += cf[t * 4 + 1] * dv4[1];
            o += cf[t * 4 + 2] * dv4[2];
            o += cf[t * 4 + 3] * dv4[3];
            __builtin_nontemporal_store(o, (f32x4*)(ob + (size_t)t * NN * DD + dp * 2));
        }
    }
}

extern "C" void kernel_launch(void* const* d_in, const int* in_sizes, int n_in,
                              void* d_out, int out_size, void* d_ws, size_t ws_size,
                              hipStream_t stream) {
    const float* residuals = (const float*)d_in[0];
    const float* gamma     = (const float*)d_in[1];
    const float* daf       = (const float*)d_in[2];
    const float* sa        = (const float*)d_in[3];
    const float* pbs       = (const float*)d_in[4];
    const float* rsc       = (const float*)d_in[5];
    const float* dbf       = (const float*)d_in[6];
    const float* sb        = (const float*)d_in[7];
    const float* hps       = (const float*)d_in[8];
    float* out = (float*)d_out;

    unsigned short* Wfrag = (unsigned short*)d_ws;  // 32*8192 bf16 = 512 KiB, fragment order

    k0_prep<<<1024, 256, 0, stream>>>(gamma, daf, dbf, Wfrag);
    kf<<<NROWS / 4, 512, 0, stream>>>(residuals, Wfrag, sa, sb, pbs, rsc, hps, out);
}

// Round 16
// 170.507 us; speedup vs baseline: 1.0334x; 1.0334x over previous
//
#include <hip/hip_runtime.h>
#include <hip/hip_bf16.h>

typedef float f32x4 __attribute__((ext_vector_type(4)));
typedef float f32x16 __attribute__((ext_vector_type(16)));
typedef unsigned int u32;
typedef u32 u32x2 __attribute__((ext_vector_type(2)));
typedef u32 u32x4 __attribute__((ext_vector_type(4)));
typedef short bf16x8 __attribute__((ext_vector_type(8)));

#define SD 8192      // S*D
#define NROWS 8192   // B*N
#define NN 4096      // N
#define DD 2048      // D
#define DTP 4104     // padded u32 row stride for dT

__device__ __forceinline__ u32 bfr(float f) {   // f32 -> bf16 bits, RNE (K0 only)
    u32 u = __float_as_uint(f);
    return (u + 0x7fffu + ((u >> 16) & 1u)) >> 16;
}
__device__ __forceinline__ float blo(u32 u) { return __uint_as_float(u << 16); }
__device__ __forceinline__ float bhi(u32 u) { return __uint_as_float(u & 0xffff0000u); }

// K0: weights in MFMA B-fragment order (R14-verified):
//   Wfrag[((wv*64+st)*64+lane)*8+e] = W[k=lane&31][j=wv*1024+st*16+((lane>>5)&1)*8+e]
__global__ void k0_prep(const float* __restrict__ gamma,
                        const float* __restrict__ daf,
                        const float* __restrict__ dbf,
                        unsigned short* __restrict__ Wfrag) {
    int idx = blockIdx.x * 256 + threadIdx.x;
    if (idx >= 32 * SD) return;
    const int e    = idx & 7;
    const int lane = (idx >> 3) & 63;
    const int st   = (idx >> 9) & 63;
    const int wv   = idx >> 15;
    const int outk = lane & 31;
    const int j    = wv * 1024 + st * 16 + ((lane >> 5) & 1) * 8 + e;
    unsigned short v = 0;
    if (outk < 24) {
        float g = gamma[j] + 1.0f;
        float w = (outk < 20) ? daf[j * 20 + outk] : dbf[j * 4 + (outk - 20)];
        v = (unsigned short)bfr(w * g);
    }
    Wfrag[idx] = v;
}

// KF: fused; wave-private merged P1+P2 with QUEUE-ORDER-CORRECT issue
// (R15 lesson: vmcnt is in-order — issuing HBM loads before B loads forces
// every MFMA's B-wait to drain HBM. Fix: per segment issue B first, consume
// V(s), THEN issue V(s+1); all waits then keep younger HBM loads in flight).
// Wave wv owns j-slice [wv*1024,+1024) of all 4 rows, 4 segments of 256 j.
// Sections pinned with sched_barrier(0) so the scheduler cannot hoist loads
// across segments (spill discipline, R10). No barriers until pc-reduce.
__global__ __launch_bounds__(512) void kf(const float* __restrict__ res,
                                          const unsigned short* __restrict__ Wfrag,
                                          const float* __restrict__ sa,
                                          const float* __restrict__ sb,
                                          const float* __restrict__ pbs,
                                          const float* __restrict__ rsc,
                                          const float* __restrict__ hps,
                                          float* __restrict__ out) {
    __shared__ u32 dTp[4][DTP];        // packed bf16x2; 65.7 KiB
    __shared__ float pc[8][4][32];     // per-wave partial C
    __shared__ float red[4][32];
    __shared__ float ssqp[8][4];       // per-wave partial ssq per row
    __shared__ float coefS[4][16];

    const int tid  = threadIdx.x;
    const int wv   = tid >> 6;
    const int lane = tid & 63;
    const int row0 = blockIdx.x * 4;
    const int b    = row0 >> 12;
    const int n0   = row0 & (NN - 1);
    const int r    = tid >> 7;          // P4 row 0..3
    const int rem  = tid & 127;

    // ---------- P1+P2: wave-private, queue-ordered pipeline ----------
    {
        const int sp = wv >> 1;
        const int d0 = (wv & 1) * 1024;
        const float* rp0 = res + ((size_t)(b * 4 + sp) * NN + n0) * DD + d0 + lane * 4;
        const float* rp1 = rp0 + DD;
        const float* rp2 = rp0 + 2 * DD;
        const float* rp3 = rp0 + 3 * DD;
        const u32* abase = &dTp[lane & 3][wv * 512 + (lane >> 5) * 4];
        const unsigned short* wbase = Wfrag + ((size_t)wv * 4096 + lane) * 8;

        f32x16 acc;
#pragma unroll
        for (int i = 0; i < 16; ++i) acc[i] = 0.f;
        float sq0 = 0.f, sq1 = 0.f, sq2 = 0.f, sq3 = 0.f;

        f32x4 v0 = *(const f32x4*)rp0;      // V(0)
        f32x4 v1 = *(const f32x4*)rp1;
        f32x4 v2 = *(const f32x4*)rp2;
        f32x4 v3 = *(const f32x4*)rp3;

#define SEGX(S)                                                               \
        {                                                                     \
            u32x4 bua[8], bub[8];                                             \
            _Pragma("unroll")                                                 \
            for (int i = 0; i < 8; ++i)                                       \
                bua[i] = *(const u32x4*)(wbase + (size_t)((S) * 16 + i) * 512); \
            _Pragma("unroll")                                                 \
            for (int i = 0; i < 8; ++i)                                       \
                bub[i] = *(const u32x4*)(wbase + (size_t)((S) * 16 + 8 + i) * 512); \
            __builtin_amdgcn_sched_barrier(0);                                \
            /* FIN(S): consume v (vmcnt keeps bua/bub in flight) */           \
            sq0 += v0.x * v0.x + v0.y * v0.y + v0.z * v0.z + v0.w * v0.w;     \
            sq1 += v1.x * v1.x + v1.y * v1.y + v1.z * v1.z + v1.w * v1.w;     \
            sq2 += v2.x * v2.x + v2.y * v2.y + v2.z * v2.z + v2.w * v2.w;     \
            sq3 += v3.x * v3.x + v3.y * v3.y + v3.z * v3.z + v3.w * v3.w;     \
            {                                                                 \
                const int o = wv * 512 + (S) * 128 + lane * 2;                \
                u32 lo, hi;                                                   \
                asm("v_cvt_pk_bf16_f32 %0, %1, %2" : "=v"(lo) : "v"(v0.x), "v"(v0.y)); \
                asm("v_cvt_pk_bf16_f32 %0, %1, %2" : "=v"(hi) : "v"(v0.z), "v"(v0.w)); \
                *(u32x2*)&dTp[0][o] = (u32x2){lo, hi};                        \
                asm("v_cvt_pk_bf16_f32 %0, %1, %2" : "=v"(lo) : "v"(v1.x), "v"(v1.y)); \
                asm("v_cvt_pk_bf16_f32 %0, %1, %2" : "=v"(hi) : "v"(v1.z), "v"(v1.w)); \
                *(u32x2*)&dTp[1][o] = (u32x2){lo, hi};                        \
                asm("v_cvt_pk_bf16_f32 %0, %1, %2" : "=v"(lo) : "v"(v2.x), "v"(v2.y)); \
                asm("v_cvt_pk_bf16_f32 %0, %1, %2" : "=v"(hi) : "v"(v2.z), "v"(v2.w)); \
                *(u32x2*)&dTp[2][o] = (u32x2){lo, hi};                        \
                asm("v_cvt_pk_bf16_f32 %0, %1, %2" : "=v"(lo) : "v"(v3.x), "v"(v3.y)); \
                asm("v_cvt_pk_bf16_f32 %0, %1, %2" : "=v"(hi) : "v"(v3.z), "v"(v3.w)); \
                *(u32x2*)&dTp[3][o] = (u32x2){lo, hi};                        \
            }                                                                 \
            __builtin_amdgcn_sched_barrier(0);                                \
            /* V(S+1) into the freed v regs (issued AFTER B loads) */         \
            if ((S) < 3) {                                                    \
                v0 = *(const f32x4*)(rp0 + ((S) + 1) * 256);                  \
                v1 = *(const f32x4*)(rp1 + ((S) + 1) * 256);                  \
                v2 = *(const f32x4*)(rp2 + ((S) + 1) * 256);                  \
                v3 = *(const f32x4*)(rp3 + ((S) + 1) * 256);                  \
            }                                                                 \
            __builtin_amdgcn_sched_barrier(0);                                \
            _Pragma("unroll")                                                 \
            for (int i = 0; i < 8; ++i) {                                     \
                const u32x4 au = *(const u32x4*)(abase + ((S) * 16 + i) * 8); \
                acc = __builtin_amdgcn_mfma_f32_32x32x16_bf16(                \
                    __builtin_bit_cast(bf16x8, au),                           \
                    __builtin_bit_cast(bf16x8, bua[i]), acc, 0, 0, 0);        \
            }                                                                 \
            __builtin_amdgcn_sched_barrier(0);                                \
            _Pragma("unroll")                                                 \
            for (int i = 0; i < 8; ++i) {                                     \
                const u32x4 au = *(const u32x4*)(abase + ((S) * 16 + 8 + i) * 8); \
                acc = __builtin_amdgcn_mfma_f32_32x32x16_bf16(                \
                    __builtin_bit_cast(bf16x8, au),                           \
                    __builtin_bit_cast(bf16x8, bub[i]), acc, 0, 0, 0);        \
            }                                                                 \
            __builtin_amdgcn_sched_barrier(0);                                \
        }

        SEGX(0)
        SEGX(1)
        SEGX(2)
        SEGX(3)
#undef SEGX

#define RED64(x) x += __shfl_xor(x, 1); x += __shfl_xor(x, 2); x += __shfl_xor(x, 4); \
                 x += __shfl_xor(x, 8); x += __shfl_xor(x, 16); x += __shfl_xor(x, 32);
        RED64(sq0) RED64(sq1) RED64(sq2) RED64(sq3)
#undef RED64
        if (lane == 0) {
            ssqp[wv][0] = sq0; ssqp[wv][1] = sq1;
            ssqp[wv][2] = sq2; ssqp[wv][3] = sq3;
        }
        if (lane < 32) {
#pragma unroll
            for (int gg = 0; gg < 4; ++gg) pc[wv][gg][lane] = acc[gg];
        }
    }
    __syncthreads();
    if (tid < 128) {
        const int rr = tid >> 5, c = tid & 31;
        float s = 0.f;
#pragma unroll
        for (int w = 0; w < 8; ++w) s += pc[w][rr][c];
        red[rr][c] = s;
    }
    __syncthreads();

    // ---------- P3: sinkhorn + coeff (wave 0; 4 rows x 16 lanes) ----------
    if (wv == 0) {
        const int rr = lane >> 4, l = lane & 15, s = l >> 2, t = l & 3;
        float ssqr = 0.f;
#pragma unroll
        for (int w = 0; w < 8; ++w) ssqr += ssqp[w][rr];
        const float scale = 90.50966799187809f / fmaxf(sqrtf(ssqr), 1e-12f);
        const float P  = red[rr][s * 5 + t + 1];
        const float P0 = red[rr][s * 5];
        const float Pb = red[rr][20 + t];
        float la = scale * P * rsc[0] + sa[s * 5 + t + 1];
        const float a0 = scale * P0 * pbs[0] + sa[s * 5];
        const float ap = 1.f / (1.f + __expf(-a0));
        const float bt = 2.f / (1.f + __expf(-(scale * Pb * hps[0] + sb[t])));
#pragma unroll
        for (int it = 0; it < 20; ++it) {
            float m = fmaxf(la, __shfl_xor(la, 4));
            m = fmaxf(m, __shfl_xor(m, 8));
            float e = __expf(la - m);
            e += __shfl_xor(e, 4);
            e += __shfl_xor(e, 8);
            la -= m + __logf(e);
            m = fmaxf(la, __shfl_xor(la, 1));
            m = fmaxf(m, __shfl_xor(m, 2));
            e = __expf(la - m);
            e += __shfl_xor(e, 1);
            e += __shfl_xor(e, 2);
            la -= m + __logf(e);
        }
        coefS[rr][t * 4 + s] = ap * bt + __expf(la);
    }
    __syncthreads();

    // ---------- P4: mix + store (rolled, packed FMA) ----------
    float cf[16];
#pragma unroll
    for (int i = 0; i < 16; ++i) cf[i] = coefS[r][i];
    float* ob = out + ((size_t)(b * 4) * NN + (n0 + r)) * DD;
#pragma unroll 1
    for (int qq = 0; qq < 4; ++qq) {
        const int dp = (rem + 128 * qq) * 2;    // u32 index within s-plane
        f32x4 dv4[4];
#pragma unroll
        for (int s = 0; s < 4; ++s) {
            u32x2 u = *(const u32x2*)&dTp[r][s * 1024 + dp];
            dv4[s] = (f32x4){blo(u[0]), bhi(u[0]), blo(u[1]), bhi(u[1])};
        }
#pragma unroll
        for (int t = 0; t < 4; ++t) {
            f32x4 o = cf[t * 4 + 0] * dv4[0];
            o += cf[t * 4 + 1] * dv4[1];
            o += cf[t * 4 + 2] * dv4[2];
            o += cf[t * 4 + 3] * dv4[3];
            __builtin_nontemporal_store(o, (f32x4*)(ob + (size_t)t * NN * DD + dp * 2));
        }
    }
}

extern "C" void kernel_launch(void* const* d_in, const int* in_sizes, int n_in,
                              void* d_out, int out_size, void* d_ws, size_t ws_size,
                              hipStream_t stream) {
    const float* residuals = (const float*)d_in[0];
    const float* gamma     = (const float*)d_in[1];
    const float* daf       = (const float*)d_in[2];
    const float* sa        = (const float*)d_in[3];
    const float* pbs       = (const float*)d_in[4];
    const float* rsc       = (const float*)d_in[5];
    const float* dbf       = (const float*)d_in[6];
    const float* sb        = (const float*)d_in[7];
    const float* hps       = (const float*)d_in[8];
    float* out = (float*)d_out;

    unsigned short* Wfrag = (unsigned short*)d_ws;  // 512 KiB, fragment order

    k0_prep<<<1024, 256, 0, stream>>>(gamma, daf, dbf, Wfrag);
    kf<<<NROWS / 4, 512, 0, stream>>>(residuals, Wfrag, sa, sb, pbs, rsc, hps, out);
}